// Round 9
// baseline (129.772 us; speedup 1.0000x reference)
//
#include <hip/hip_runtime.h>

#define LOG64f 4.1588830833596715f
#define LOG32f 3.4657359027997265f
#define LOG16f 2.7725887222397810f

// Block = 256 threads = 64 fragments.
// Phase 1: cooperative stage of all bc rows into padded LDS. Every global
//          load is a contiguous 1KB-per-wave transaction (same geometry as
//          round 4 -- each big-array byte touched exactly once).
// Phase 2: one __syncthreads.
// Phase 3: 4 lanes per fragment, lane-local serial masked exp-sums from
//          padded LDS rows (rotated unit order to spread banks); per-lane
//          scalars; only 12 shfl_xor per 16 fragments. No dependent
//          shuffle chains, no broadcasts.
// Padding: +1 16B-unit per row -> bank spread for transposed b128 reads.

#define PAD0 68   // ints per t0 row (64 + 4)
#define PAD1 36   // ints per t1 row (32 + 4)
#define PAD2 20   // ints per t2 row (16 + 4)

__global__ __launch_bounds__(256) void frag_pos_dist_kernel(
    const int* __restrict__ bc0, const int* __restrict__ bc1, const int* __restrict__ bc2,
    const int* __restrict__ gix, const int* __restrict__ bix,
    const int* __restrict__ labels, const int* __restrict__ lci,
    const float* __restrict__ bw0, const float* __restrict__ d0,
    const float* __restrict__ bw1, const float* __restrict__ d1,
    const float* __restrict__ bw2, const float* __restrict__ d2,
    float* __restrict__ out, int N)
{
    __shared__ int sh0[64 * PAD0];
    __shared__ int sh1[64 * PAD1];
    __shared__ int sh2[64 * PAD2];

    const int tid  = threadIdx.x;
    const int base = blockIdx.x * 64;
    const int NM1  = N - 1;

    // ---------------- phase 1: cooperative staging ----------------
    // t0: 64 rows x 16 units(16B) = 1024 units, 4 per thread
    #pragma unroll
    for (int k = 0; k < 4; ++k) {
        const int u = tid + 256 * k;
        const int r = u >> 4, c = u & 15;
        const int n = min(base + r, NM1);
        const int4 v = ((const int4*)(bc0 + (size_t)n * 64))[c];
        *(int4*)&sh0[r * PAD0 + c * 4] = v;
    }
    // t1: 64 rows x 8 units = 512 units, 2 per thread
    #pragma unroll
    for (int k = 0; k < 2; ++k) {
        const int u = tid + 256 * k;
        const int r = u >> 3, c = u & 7;
        const int n = min(base + r, NM1);
        const int4 v = ((const int4*)(bc1 + (size_t)n * 32))[c];
        *(int4*)&sh1[r * PAD1 + c * 4] = v;
    }
    // t2: 64 rows x 4 units = 256 units, 1 per thread
    {
        const int u = tid;
        const int r = u >> 2, c = u & 3;
        const int n = min(base + r, NM1);
        const int4 v = ((const int4*)(bc2 + (size_t)n * 16))[c];
        *(int4*)&sh2[r * PAD2 + c * 4] = v;
    }

    __syncthreads();

    // ---------------- phase 3: per-fragment compute (4 lanes/fragment) -----
    const int f = tid >> 2;          // fragment slot 0..63
    const int q = tid & 3;           // quarter within fragment
    const int n = min(base + f, NM1);

    const int cell = lci[n];
    const int lab  = labels[cell];
    const float dva = d0[lab], dvb = d1[lab], dvc = d2[lab];
    const int g0 = gix[3 * n + 0], g1 = gix[3 * n + 1], g2 = gix[3 * n + 2];
    const int b0 = bix[3 * n + 0], b1 = bix[3 * n + 1], b2 = bix[3 * n + 2];

    // ---- track 0 (S=64): quarter q owns units q*4 .. q*4+3, rotated by f ----
    float s0 = 0.f, ub0 = 0.f;
    {
        const float4* wrow = (const float4*)(bw0 + (size_t)g0 * 64);
        #pragma unroll
        for (int k = 0; k < 4; ++k) {
            const int c  = q * 4 + ((k + f) & 3);
            const int4   cc = *(const int4*)&sh0[f * PAD0 + c * 4];
            const float4 ww = wrow[c];
            const float u0 = (cc.x > 1 ? dva : 0.f) + ww.x;
            const float u1 = (cc.y > 1 ? dva : 0.f) + ww.y;
            const float u2 = (cc.z > 1 ? dva : 0.f) + ww.z;
            const float u3 = (cc.w > 1 ? dva : 0.f) + ww.w;
            s0 += (__expf(u0) + __expf(u1)) + (__expf(u2) + __expf(u3));
            if (c == (b0 >> 2)) {
                const int r = b0 & 3;
                ub0 = r == 0 ? u0 : r == 1 ? u1 : r == 2 ? u2 : u3;
            }
        }
    }

    // ---- track 1 (S=32): quarter q owns units q*2 .. q*2+1, rotated by f ----
    float s1 = 0.f, ub1 = 0.f;
    {
        const float4* wrow = (const float4*)(bw1 + (size_t)g1 * 32);
        #pragma unroll
        for (int k = 0; k < 2; ++k) {
            const int c  = q * 2 + ((k + f) & 1);
            const int4   cc = *(const int4*)&sh1[f * PAD1 + c * 4];
            const float4 ww = wrow[c];
            const float u0 = (cc.x > 1 ? dvb : 0.f) + ww.x;
            const float u1 = (cc.y > 1 ? dvb : 0.f) + ww.y;
            const float u2 = (cc.z > 1 ? dvb : 0.f) + ww.z;
            const float u3 = (cc.w > 1 ? dvb : 0.f) + ww.w;
            s1 += (__expf(u0) + __expf(u1)) + (__expf(u2) + __expf(u3));
            if (c == (b1 >> 2)) {
                const int r = b1 & 3;
                ub1 = r == 0 ? u0 : r == 1 ? u1 : r == 2 ? u2 : u3;
            }
        }
    }

    // ---- track 2 (S=16): quarter q owns unit q ----
    float s2 = 0.f, ub2 = 0.f;
    {
        const float4* wrow = (const float4*)(bw2 + (size_t)g2 * 16);
        const int c  = q;
        const int4   cc = *(const int4*)&sh2[f * PAD2 + c * 4];
        const float4 ww = wrow[c];
        const float u0 = (cc.x > 1 ? dvc : 0.f) + ww.x;
        const float u1 = (cc.y > 1 ? dvc : 0.f) + ww.y;
        const float u2 = (cc.z > 1 ? dvc : 0.f) + ww.z;
        const float u3 = (cc.w > 1 ? dvc : 0.f) + ww.w;
        s2 = (__expf(u0) + __expf(u1)) + (__expf(u2) + __expf(u3));
        if (c == (b2 >> 2)) {
            const int r = b2 & 3;
            ub2 = r == 0 ? u0 : r == 1 ? u1 : r == 2 ? u2 : u3;
        }
    }

    // ---- reduce across the 4 lanes of each fragment ----
    s0  += __shfl_xor(s0, 1);  s0  += __shfl_xor(s0, 2);
    ub0 += __shfl_xor(ub0, 1); ub0 += __shfl_xor(ub0, 2);
    s1  += __shfl_xor(s1, 1);  s1  += __shfl_xor(s1, 2);
    ub1 += __shfl_xor(ub1, 1); ub1 += __shfl_xor(ub1, 2);
    s2  += __shfl_xor(s2, 1);  s2  += __shfl_xor(s2, 2);
    ub2 += __shfl_xor(ub2, 1); ub2 += __shfl_xor(ub2, 2);

    if (q == 0) {
        const int nout = base + f;
        if (nout < N) {
            out[nout] = (ub0 - __logf(s0) + LOG64f) +
                        (ub1 - __logf(s1) + LOG32f) +
                        (ub2 - __logf(s2) + LOG16f);
        }
    }
}

extern "C" void kernel_launch(void* const* d_in, const int* in_sizes, int n_in,
                              void* d_out, int out_size, void* d_ws, size_t ws_size,
                              hipStream_t stream) {
    const int* bc0    = (const int*)d_in[0];
    const int* bc1    = (const int*)d_in[1];
    const int* bc2    = (const int*)d_in[2];
    const int* gix    = (const int*)d_in[3];
    const int* bixp   = (const int*)d_in[4];
    const int* labels = (const int*)d_in[5];
    const int* lci    = (const int*)d_in[6];
    const float* bw0  = (const float*)d_in[7];
    const float* dv0  = (const float*)d_in[8];
    const float* bw1  = (const float*)d_in[9];
    const float* dv1  = (const float*)d_in[10];
    const float* bw2  = (const float*)d_in[11];
    const float* dv2  = (const float*)d_in[12];
    float* out = (float*)d_out;

    const int N = in_sizes[6];  // local_cell_ix has N elements
    const int blocks = (N + 63) / 64;

    frag_pos_dist_kernel<<<blocks, 256, 0, stream>>>(
        bc0, bc1, bc2, gix, bixp, labels, lci,
        bw0, dv0, bw1, dv1, bw2, dv2, out, N);
}

// Round 10
// 104.546 us; speedup vs baseline: 1.2413x; 1.2413x over previous
//
#include <hip/hip_runtime.h>

#define LOG64f 4.1588830833596715f
#define LOG32f 3.4657359027997265f
#define LOG16f 2.7725887222397810f

// Round 10: r4/r7 streaming core + index-resolution prepass.
// Prepass packs per-fragment scalars {lab, g0,b0, g1,b1, g2,b2} into an 8B
// record (lab:4b, g:10b, b:4b per track), written/read sequentially. The hot
// kernel's dependency head becomes: 8B record load -> 10 broadcasts -> bw row
// load; the 3-deep gather chain (lci->labels->d) and strided gix/bix reads
// leave the hot loop entirely. Fallback path (rec==nullptr) resolves scalars
// inline if ws_size is too small.
//
// w0 = lab | (g0<<4) | (b0<<14) | (g1<<18)   (28 bits)
// w1 = b1  | (g2<<4) | (b2<<14)              (18 bits)

__global__ __launch_bounds__(256) void prepass_kernel(
    const int* __restrict__ gix, const int* __restrict__ bix,
    const int* __restrict__ labels, const int* __restrict__ lci,
    int2* __restrict__ rec, int N)
{
    const int n = blockIdx.x * blockDim.x + threadIdx.x;
    if (n >= N) return;
    const int lab = labels[lci[n]];
    const int g0 = gix[3 * n + 0], g1 = gix[3 * n + 1], g2 = gix[3 * n + 2];
    const int b0 = bix[3 * n + 0], b1 = bix[3 * n + 1], b2 = bix[3 * n + 2];
    int2 w;
    w.x = lab | (g0 << 4) | (b0 << 14) | (g1 << 18);
    w.y = b1 | (g2 << 4) | (b2 << 14);
    rec[n] = w;
}

__device__ __forceinline__ void expsum4(const int4 c, const float4 w, const float dv,
                                        const int b, const int sub, float& s, float& ub)
{
    const float u0 = (c.x > 1 ? dv : 0.f) + w.x;
    const float u1 = (c.y > 1 ? dv : 0.f) + w.y;
    const float u2 = (c.z > 1 ? dv : 0.f) + w.z;
    const float u3 = (c.w > 1 ? dv : 0.f) + w.w;
    s  = (__expf(u0) + __expf(u1)) + (__expf(u2) + __expf(u3));
    ub = 0.f;
    if (sub == (b >> 2)) {
        const int r = b & 3;
        ub = r == 0 ? u0 : r == 1 ? u1 : r == 2 ? u2 : u3;
    }
}

__global__ __launch_bounds__(256) void frag_pos_dist_kernel(
    const int* __restrict__ bc0, const int* __restrict__ bc1, const int* __restrict__ bc2,
    const int* __restrict__ gix, const int* __restrict__ bix,
    const int* __restrict__ labels, const int* __restrict__ lci,
    const float* __restrict__ bw0, const float* __restrict__ d0,
    const float* __restrict__ bw1, const float* __restrict__ d1,
    const float* __restrict__ bw2, const float* __restrict__ d2,
    const int2* __restrict__ rec,
    float* __restrict__ out, int N)
{
    const int lane = threadIdx.x & 63;
    const int wid  = blockIdx.x * (blockDim.x >> 6) + (threadIdx.x >> 6);
    const int base = wid * 16;
    if (base >= N) return;
    const int fl = lane & 15;
    const int NM1 = N - 1;

    const int s16 = lane >> 4, s8 = lane >> 3, s4 = lane >> 2;
    const int f00 = s16, f01 = 4 + s16, f02 = 8 + s16, f03 = 12 + s16;
    const int f10 = s8,  f11 = 8 + s8;
    const int f20 = s4;
    const int sub0 = lane & 15, sub1 = lane & 7, sub2 = lane & 3;

    // ---------- phase 0: bc streaming loads (independent, contiguous 1KB) ----
    const int n00 = min(base +      s16, NM1), n01 = min(base +  4 + s16, NM1),
              n02 = min(base +  8 + s16, NM1), n03 = min(base + 12 + s16, NM1);
    const int n10 = min(base +       s8, NM1), n11 = min(base +  8 +  s8, NM1);
    const int n20 = min(base +       s4, NM1);

    const int4 c00 = ((const int4*)(bc0 + (size_t)n00 * 64))[sub0];
    const int4 c01 = ((const int4*)(bc0 + (size_t)n01 * 64))[sub0];
    const int4 c02 = ((const int4*)(bc0 + (size_t)n02 * 64))[sub0];
    const int4 c03 = ((const int4*)(bc0 + (size_t)n03 * 64))[sub0];
    const int4 c10 = ((const int4*)(bc1 + (size_t)n10 * 32))[sub1];
    const int4 c11 = ((const int4*)(bc1 + (size_t)n11 * 32))[sub1];
    const int4 c20 = ((const int4*)(bc2 + (size_t)n20 * 16))[sub2];

    // ---------- phase A: packed per-fragment scalars ----------
    const int nf = min(base + fl, NM1);
    int w0, w1;
    if (rec) {
        const int2 pw = rec[nf];
        w0 = pw.x; w1 = pw.y;
    } else {
        const int lab = labels[lci[nf]];
        const int g0 = gix[3 * nf + 0], g1 = gix[3 * nf + 1], g2 = gix[3 * nf + 2];
        const int b0 = bix[3 * nf + 0], b1 = bix[3 * nf + 1], b2 = bix[3 * nf + 2];
        w0 = lab | (g0 << 4) | (b0 << 14) | (g1 << 18);
        w1 = b1 | (g2 << 4) | (b2 << 14);
    }

    // ---------- phase B: broadcasts + unpack + tiny d-table gathers ----------
    const int W000 = __shfl(w0, f00), W001 = __shfl(w0, f01),
              W002 = __shfl(w0, f02), W003 = __shfl(w0, f03);
    const int W010 = __shfl(w0, f10), W110 = __shfl(w1, f10);
    const int W011 = __shfl(w0, f11), W111 = __shfl(w1, f11);
    const int W020 = __shfl(w0, f20), W120 = __shfl(w1, f20);

    const float dv00 = d0[W000 & 15]; const int g00 = (W000 >> 4) & 1023, b00 = (W000 >> 14) & 15;
    const float dv01 = d0[W001 & 15]; const int g01 = (W001 >> 4) & 1023, b01 = (W001 >> 14) & 15;
    const float dv02 = d0[W002 & 15]; const int g02 = (W002 >> 4) & 1023, b02 = (W002 >> 14) & 15;
    const float dv03 = d0[W003 & 15]; const int g03 = (W003 >> 4) & 1023, b03 = (W003 >> 14) & 15;
    const float dv10 = d1[W010 & 15]; const int g10 = (W010 >> 18) & 1023, b10 = W110 & 15;
    const float dv11 = d1[W011 & 15]; const int g11 = (W011 >> 18) & 1023, b11 = W111 & 15;
    const float dv20 = d2[W020 & 15]; const int g20 = (W120 >> 4) & 1023, b20 = (W120 >> 14) & 15;

    // own (owner-lane) selected positions
    const int b0o = (w0 >> 14) & 15;
    const int b1o = w1 & 15;
    const int b2o = (w1 >> 14) & 15;

    // ---------- phase C: baseline row loads (L2-resident tables) ----------
    const float4 w00 = ((const float4*)(bw0 + (size_t)g00 * 64))[sub0];
    const float4 w01 = ((const float4*)(bw0 + (size_t)g01 * 64))[sub0];
    const float4 w02 = ((const float4*)(bw0 + (size_t)g02 * 64))[sub0];
    const float4 w03 = ((const float4*)(bw0 + (size_t)g03 * 64))[sub0];
    const float4 w10 = ((const float4*)(bw1 + (size_t)g10 * 32))[sub1];
    const float4 w11 = ((const float4*)(bw1 + (size_t)g11 * 32))[sub1];
    const float4 w20 = ((const float4*)(bw2 + (size_t)g20 * 16))[sub2];

    // ---------- phase D: exp-sums + segmented reductions ----------
    float s00, u00, s01, u01, s02, u02, s03, u03;
    expsum4(c00, w00, dv00, b00, sub0, s00, u00);
    expsum4(c01, w01, dv01, b01, sub0, s01, u01);
    expsum4(c02, w02, dv02, b02, sub0, s02, u02);
    expsum4(c03, w03, dv03, b03, sub0, s03, u03);
    #pragma unroll
    for (int off = 1; off <= 8; off <<= 1) {
        s00 += __shfl_xor(s00, off); s01 += __shfl_xor(s01, off);
        s02 += __shfl_xor(s02, off); s03 += __shfl_xor(s03, off);
    }
    float s10, u10, s11, u11;
    expsum4(c10, w10, dv10, b10, sub1, s10, u10);
    expsum4(c11, w11, dv11, b11, sub1, s11, u11);
    #pragma unroll
    for (int off = 1; off <= 4; off <<= 1) {
        s10 += __shfl_xor(s10, off); s11 += __shfl_xor(s11, off);
    }
    float s20, u20;
    expsum4(c20, w20, dv20, b20, sub2, s20, u20);
    s20 += __shfl_xor(s20, 1); s20 += __shfl_xor(s20, 2);

    // ---------- gather S (segment sums) and U (direct from holder lane) -----
    const int  src0 = (fl & 3) << 4;
    const float m00 = __shfl(s00, src0), m01 = __shfl(s01, src0),
                m02 = __shfl(s02, src0), m03 = __shfl(s03, src0);
    const int j0 = fl >> 2;
    const float S0 = j0 == 0 ? m00 : j0 == 1 ? m01 : j0 == 2 ? m02 : m03;
    const int  h0 = src0 + (b0o >> 2);
    const float x00 = __shfl(u00, h0), x01 = __shfl(u01, h0),
                x02 = __shfl(u02, h0), x03 = __shfl(u03, h0);
    const float U0 = j0 == 0 ? x00 : j0 == 1 ? x01 : j0 == 2 ? x02 : x03;

    const int  src1 = (fl & 7) << 3;
    const float m10 = __shfl(s10, src1), m11 = __shfl(s11, src1);
    const float S1 = (fl >> 3) == 0 ? m10 : m11;
    const int  h1 = src1 + (b1o >> 2);
    const float x10 = __shfl(u10, h1), x11 = __shfl(u11, h1);
    const float U1 = (fl >> 3) == 0 ? x10 : x11;

    const float S2 = __shfl(s20, fl << 2);
    const float U2 = __shfl(u20, (fl << 2) + (b2o >> 2));

    const float acc = (U0 - __logf(S0) + LOG64f) +
                      (U1 - __logf(S1) + LOG32f) +
                      (U2 - __logf(S2) + LOG16f);

    if (lane < 16) {
        const int n = base + lane;
        if (n < N) out[n] = acc;
    }
}

extern "C" void kernel_launch(void* const* d_in, const int* in_sizes, int n_in,
                              void* d_out, int out_size, void* d_ws, size_t ws_size,
                              hipStream_t stream) {
    const int* bc0    = (const int*)d_in[0];
    const int* bc1    = (const int*)d_in[1];
    const int* bc2    = (const int*)d_in[2];
    const int* gix    = (const int*)d_in[3];
    const int* bixp   = (const int*)d_in[4];
    const int* labels = (const int*)d_in[5];
    const int* lci    = (const int*)d_in[6];
    const float* bw0  = (const float*)d_in[7];
    const float* dv0  = (const float*)d_in[8];
    const float* bw1  = (const float*)d_in[9];
    const float* dv1  = (const float*)d_in[10];
    const float* bw2  = (const float*)d_in[11];
    const float* dv2  = (const float*)d_in[12];
    float* out = (float*)d_out;

    const int N = in_sizes[6];  // local_cell_ix has N elements

    int2* rec = nullptr;
    if (ws_size >= (size_t)N * sizeof(int2)) {
        rec = (int2*)d_ws;
        prepass_kernel<<<(N + 255) / 256, 256, 0, stream>>>(
            gix, bixp, labels, lci, rec, N);
    }

    const int fragsPerBlock = 64;       // 4 waves * 16 fragments
    const int blocks = (N + fragsPerBlock - 1) / fragsPerBlock;
    frag_pos_dist_kernel<<<blocks, 256, 0, stream>>>(
        bc0, bc1, bc2, gix, bixp, labels, lci,
        bw0, dv0, bw1, dv1, bw2, dv2, rec, out, N);
}